// Round 3
// baseline (562.187 us; speedup 1.0000x reference)
//
#include <hip/hip_runtime.h>
#include <hip/hip_bf16.h>

// Problem constants (from reference setup): B=4, S=1024, D=768, L=32
#define BB 4
#define SS 1024
#define DD 768
#define LL 32

// ---------------------------------------------------------------------------
// Kernel 1: compute h_score (+bias) and d_score.
//   h[b,l,i] = dot(head[b,i,:], W[l, 0:768])   + bias[l]
//   d[b,l,j] = dot(dep [b,j,:], W[l, 768:1536])
// One block per (b, i). 256 threads: 64 outputs (32 h + 32 d) x 4 sub-lanes.
// ---------------------------------------------------------------------------
__global__ __launch_bounds__(256) void ala_scores_kernel(
    const float* __restrict__ head,
    const float* __restrict__ dep,
    const float* __restrict__ W,     // [L][2*D]
    const float* __restrict__ bias,  // [L]
    float* __restrict__ hb,          // [B][L][S]  (h_score + bias)
    float* __restrict__ ds)          // [B][L][S]
{
    __shared__ __align__(16) float hrow[DD];
    __shared__ __align__(16) float drow[DD];

    const int bi = blockIdx.x;           // 0 .. B*S-1
    const int b  = bi >> 10;             // / S
    const int i  = bi & (SS - 1);

    const float* hp = head + (size_t)bi * DD;
    const float* dp = dep  + (size_t)bi * DD;
    for (int t = threadIdx.x; t < DD; t += 256) {
        hrow[t] = hp[t];
        drow[t] = dp[t];
    }
    __syncthreads();

    const int out  = threadIdx.x >> 2;   // 0..63
    const int sub  = threadIdx.x & 3;    // 0..3
    const int l    = out & (LL - 1);
    const bool ish = out < LL;

    const float* row = ish ? hrow : drow;
    const float* w   = W + (size_t)l * (2 * DD) + (ish ? 0 : DD);

    float sum = 0.f;
    // 768 floats = 192 float4s; each sub-lane takes every 4th float4.
    #pragma unroll 4
    for (int d4 = sub; d4 < DD / 4; d4 += 4) {
        const float4 r  = *reinterpret_cast<const float4*>(row + d4 * 4);
        const float4 ww = *reinterpret_cast<const float4*>(w   + d4 * 4);
        sum += r.x * ww.x + r.y * ww.y + r.z * ww.z + r.w * ww.w;
    }
    // reduce across the 4 sub-lanes (contiguous lanes within the wave)
    sum += __shfl_xor(sum, 1);
    sum += __shfl_xor(sum, 2);

    if (sub == 0) {
        const size_t idx = ((size_t)b * LL + l) * SS + i;
        if (ish) hb[idx] = sum + bias[l];
        else     ds[idx] = sum;
    }
}

// ---------------------------------------------------------------------------
// Kernel 2: emit out[b,l,i,j] = hb[b,l,i] + ds[b,l,j].
// One block per (b,l,i) row of S floats; 256 threads x float4 = 1024 floats.
// ds row (4 KB) is L1-resident (reused S times per (b,l)).
// ---------------------------------------------------------------------------
__global__ __launch_bounds__(256) void ala_emit_kernel(
    const float* __restrict__ hb,    // [B*L*S]
    const float* __restrict__ ds,    // [B*L*S]
    float* __restrict__ out)         // [B*L*S*S]
{
    const int row = blockIdx.x;          // 0 .. B*L*S-1
    const int bl  = row >> 10;           // / S
    const float h = hb[row];

    const float4* dsr = reinterpret_cast<const float4*>(ds + (size_t)bl * SS);
    const float4  v   = dsr[threadIdx.x];
    float4 o;
    o.x = h + v.x; o.y = h + v.y; o.z = h + v.z; o.w = h + v.w;
    reinterpret_cast<float4*>(out)[(size_t)row * (SS / 4) + threadIdx.x] = o;
}

extern "C" void kernel_launch(void* const* d_in, const int* in_sizes, int n_in,
                              void* d_out, int out_size, void* d_ws, size_t ws_size,
                              hipStream_t stream) {
    (void)in_sizes; (void)n_in; (void)out_size; (void)ws_size;

    const float* head = (const float*)d_in[0];
    const float* dep  = (const float*)d_in[1];
    const float* W    = (const float*)d_in[2];
    const float* bias = (const float*)d_in[3];
    float* out = (float*)d_out;

    float* hb = (float*)d_ws;                 // B*L*S floats = 512 KB
    float* ds = hb + (size_t)BB * LL * SS;    // another 512 KB

    ala_scores_kernel<<<BB * SS, 256, 0, stream>>>(head, dep, W, bias, hb, ds);
    ala_emit_kernel<<<BB * LL * SS, 256, 0, stream>>>(hb, ds, out);
}